// Round 25
// baseline (509.407 us; speedup 1.0000x reference)
//
#include <hip/hip_runtime.h>
#include <math.h>

#define BATCH 65536
#define FDIM 16
#define CDIM 128
#define HDIM 256
#define NL 8
#define KBINS 8
#define TDIM 8
#define PD 23
#define TBV 3.0f
#define K1 160      // GEMM1 K: 128 ctx + 8 xi + 24 zero
#define N3 184      // real N of GEMM3
#define N3P 192     // padded N of GEMM3
#define PSTR 197    // p LDS row stride (f32 words)
#define MR 64       // rows per row-block
#define XSTR 40     // sXi row stride (f16)

typedef _Float16 f16;
typedef __attribute__((ext_vector_type(8))) _Float16 f16x8;
typedef __attribute__((ext_vector_type(4))) float f32x4;

// ---------------- weight conversion (transposed to [N][K], split hi/lo) ----
__global__ __launch_bounds__(256)
void conv_w1_kernel(const float* __restrict__ W1,
                    f16* __restrict__ Wh, f16* __restrict__ Wl) {
    int idx = blockIdx.x * 256 + threadIdx.x;
    if (idx >= NL * HDIM * K1) return;
    int l = idx / (HDIM * K1);
    int rem = idx - l * (HDIM * K1);
    int n = rem / K1;
    int k = rem - n * K1;
    int row = (k < 128) ? (8 + k) : ((k < 136) ? (k - 128) : -1);
    float v = (row >= 0) ? W1[((size_t)l * 136 + row) * HDIM + n] : 0.f;
    f16 hv = (f16)v;
    Wh[idx] = hv; Wl[idx] = (f16)(v - (float)hv);
}

__global__ __launch_bounds__(256)
void conv_w2_kernel(const float* __restrict__ W2,
                    f16* __restrict__ Wh, f16* __restrict__ Wl) {
    int idx = blockIdx.x * 256 + threadIdx.x;
    if (idx >= NL * HDIM * HDIM) return;
    int l = idx / (HDIM * HDIM);
    int rem = idx - l * (HDIM * HDIM);
    int n = rem >> 8;
    int k = rem & 255;
    float v = W2[((size_t)l * HDIM + k) * HDIM + n];
    f16 hv = (f16)v;
    Wh[idx] = hv; Wl[idx] = (f16)(v - (float)hv);
}

__global__ __launch_bounds__(256)
void conv_w3_kernel(const float* __restrict__ W3,
                    f16* __restrict__ Wh, f16* __restrict__ Wl) {
    int idx = blockIdx.x * 256 + threadIdx.x;
    if (idx >= NL * N3P * HDIM) return;
    int l = idx / (N3P * HDIM);
    int rem = idx - l * (N3P * HDIM);
    int n = rem >> 8;
    int k = rem & 255;
    float v = (n < N3) ? W3[((size_t)l * HDIM + k) * N3 + n] : 0.f;
    f16 hv = (f16)v;
    Wh[idx] = hv; Wl[idx] = (f16)(v - (float)hv);
}

__global__ __launch_bounds__(256)
void conv_ctx_kernel(const float* __restrict__ ctx,
                     f16* __restrict__ ch, f16* __restrict__ cl) {
    size_t idx = ((size_t)blockIdx.x * 256 + threadIdx.x) * 4;
    if (idx >= (size_t)BATCH * CDIM) return;
    float4 v = *(const float4*)&ctx[idx];
    f16 h;
    h = (f16)v.x; ch[idx + 0] = h; cl[idx + 0] = (f16)(v.x - (float)h);
    h = (f16)v.y; ch[idx + 1] = h; cl[idx + 1] = (f16)(v.y - (float)h);
    h = (f16)v.z; ch[idx + 2] = h; cl[idx + 2] = (f16)(v.z - (float)h);
    h = (f16)v.w; ch[idx + 3] = h; cl[idx + 3] = (f16)(v.w - (float)h);
}

__device__ __forceinline__ float softplusf(float v) {
    return fmaxf(v, 0.f) + log1pf(__expf(-fabsf(v)));
}

__device__ __forceinline__ void gld16(const f16* src, f16* dst) {
    __builtin_amdgcn_global_load_lds(
        (const __attribute__((address_space(1))) unsigned int*)src,
        (__attribute__((address_space(3))) unsigned int*)dst, 16, 0, 0);
}

template<int N> __device__ __forceinline__ void vmw() {
    asm volatile("s_waitcnt vmcnt(%0)" :: "n"(N) : "memory");
}
__device__ __forceinline__ void lgkmw() {
    asm volatile("s_waitcnt lgkmcnt(0)" ::: "memory");
}
__device__ __forceinline__ void barr() {
    __builtin_amdgcn_s_barrier();
    __builtin_amdgcn_sched_barrier(0);
}
__device__ __forceinline__ void lgkm_bar() {
    asm volatile("s_waitcnt lgkmcnt(0)" ::: "memory");
    __builtin_amdgcn_s_barrier();
    __builtin_amdgcn_sched_barrier(0);
}

// ---------------- fused flow kernel ----------------
// Persistent: grid 256 (1 WG/CU), 512 threads (8 waves). Each wave owns a
// col slice; private 2-buf LDS weight tiles (depth-1, counted vmcnt, no
// k-loop barriers). Dedicated LDS: sCtx resident per row-block, sH, p
// overlays the (dead) wave-buffer area. G3 split 4x2 + 4x1 col-tiles.
// B swizzle: 2-way (free) bank access. Fast transcendentals in spline.
// Syncs: 7/layer — xi-split folded into rebuild, biases in per-wave VGPRs
// (bias loads are older than staging loads in the vmcnt queue, so counted
// waits still cover the right buffers).
__global__ __launch_bounds__(512, 1)
void flow_kernel(const float* __restrict__ in,
                 const f16* __restrict__ ctxh, const f16* __restrict__ ctxl,
                 const f16* __restrict__ W1h, const f16* __restrict__ W1l,
                 const f16* __restrict__ W2h, const f16* __restrict__ W2l,
                 const f16* __restrict__ W3h, const f16* __restrict__ W3l,
                 const float* __restrict__ b1, const float* __restrict__ b2,
                 const float* __restrict__ b3, const int* __restrict__ perms,
                 float* __restrict__ out) {
    __shared__ __align__(16) f16 sCtx[16384];        // 32K resident ctx (2 planes)
    __shared__ __align__(16) char warena[65536];     // 8 waves x 2 x 4KB B bufs
    __shared__ __align__(16) f16 sH[16384];          // 32K h1/h2
    __shared__ __align__(16) f16 sXi[2][MR * XSTR];  // 10.2K
    __shared__ float sX[2][MR][17];
    __shared__ float sY[MR][9];
    __shared__ float sLd[MR][9];
    __shared__ float sLdet[MR];
    __shared__ int   sPerm[(NL - 1) * FDIM];

    float* sP = (float*)warena;                      // 64 x PSTR fp32 overlay

    const int tid = threadIdx.x;
    const int lane = tid & 63;
    const int w = tid >> 6;                      // 0..7
    const int lr = lane & 15, lh = lane >> 4;
    const int bid = blockIdx.x;
    const int wgid = (bid & 7) * 32 + (bid >> 3);   // XCD swizzle, grid 256
    const int wcol0 = w * 32;                    // G1/G2 col slice
    const int wc3 = (w < 4) ? w * 32 : 128 + (w - 4) * 16;   // G3 col base

    char* const wbuf = warena + w * 8192;        // 2 x 4KB private bufs

    // B read byte offset within tile for local col lc, k-half lh
    auto bRd = [&](int lc) -> int {
        return lc * 64 + (((lh + (lc >> 1)) & 3) << 4);
    };

    // stage wave's own NC-col B tile (k-tile kt) into private buf b.
    // slot position pos of col c holds k-segment (pos - (c>>1))&3.
    auto stageB = [&](const f16* Wh, const f16* Wl, int b, int kt, int KD,
                      int colBase, int NC) {
        char* dst = wbuf + b * 4096;
        #pragma unroll
        for (int ii = 0; ii < 2; ++ii) {
            if (ii * 16 < NC) {
                int si = ii * 64 + lane;
                int c = si >> 2, pos = si & 3;
                int seg = (pos - (c >> 1)) & 3;
                const f16* sh = Wh + (size_t)(colBase + c) * KD + kt * 32 + seg * 8;
                const f16* sl = Wl + (size_t)(colBase + c) * KD + kt * 32 + seg * 8;
                gld16(sh, (f16*)(dst + ii * 1024 + lane * 16));
                gld16(sl, (f16*)(dst + NC * 64 + ii * 1024 + lane * 16));
            }
        }
    };

    for (int rb = 0; rb < 4; ++rb) {
        const int rbase = (rb * 256 + wgid) * MR;
        lgkm_bar();   // protect sX/sLdet/sCtx reuse across row-blocks

        // ---- init x, ldet, perms, l=0 xi, xi pads ----
        {
            int r = tid >> 3, c2 = (tid & 7) * 2;
            float2 v = *(const float2*)&in[(size_t)(rbase + r) * FDIM + c2];
            float v0 = fminf(fmaxf(v.x, -1.f), 1.f);
            float v1 = fminf(fmaxf(v.y, -1.f), 1.f);
            sX[0][r][c2 + 0] = v0;
            sX[0][r][c2 + 1] = v1;
            // layer 0: idn = odd features -> xi[k] = x[2k+1]; k = tid&7
            f16 hx = (f16)v1;
            sXi[0][r * XSTR + (tid & 7)] = hx;
            sXi[1][r * XSTR + (tid & 7)] = (f16)(v1 - (float)hx);
        }
        if (tid < MR) {
            sLdet[tid] = 0.f;
            #pragma unroll
            for (int k = 8; k < 32; ++k) {
                sXi[0][tid * XSTR + k] = (f16)0.f;
                sXi[1][tid * XSTR + k] = (f16)0.f;
            }
        }
        if (rb == 0 && tid < (NL - 1) * FDIM) sPerm[tid] = perms[tid];

        // ---- stage ctx ONCE per row-block (resident all layers) ----
        #pragma unroll
        for (int s = 0; s < 4; ++s) {
            int slot = s * 512 + tid;
            int p = slot >> 10, sp = slot & 1023;
            int row = sp >> 4, blk = sp & 15;
            const f16* src = (p ? ctxl : ctxh)
                           + (size_t)(rbase + row) * CDIM + (blk ^ (row & 7)) * 8;
            gld16(src, &sCtx[slot * 8]);
        }

        int cur = 0;
        for (int l = 0; l < NL; ++l) {
            lgkm_bar();   // publish rebuild/init LDS writes (sX, sXi)

            // ---- biases -> per-wave VGPRs (issued before staging: older
            //      in vmcnt queue, so counted waits still cover buffers) ----
            float bv1_0 = b1[l * HDIM + wcol0 + lr];
            float bv1_1 = b1[l * HDIM + wcol0 + 16 + lr];
            float bv2_0 = b2[l * HDIM + wcol0 + lr];
            float bv2_1 = b2[l * HDIM + wcol0 + 16 + lr];
            float bv3_0 = (wc3 + lr < N3) ? b3[l * N3 + wc3 + lr] : 0.f;
            float bv3_1 = (w < 4) ? b3[l * N3 + wc3 + 16 + lr] : 0.f;

            const f16* W1hL = W1h + (size_t)l * HDIM * K1;
            const f16* W1lL = W1l + (size_t)l * HDIM * K1;
            const f16* W2hL = W2h + (size_t)l * HDIM * HDIM;
            const f16* W2lL = W2l + (size_t)l * HDIM * HDIM;
            const f16* W3hL = W3h + (size_t)l * N3P * HDIM;
            const f16* W3lL = W3l + (size_t)l * N3P * HDIM;
            stageB(W1hL, W1lL, 0, 0, K1, wcol0, 32);
            stageB(W1hL, W1lL, 1, 1, K1, wcol0, 32);

            f32x4 acc[4][2];
            // ======= GEMM1: K=160, 5 phases, A split, NO barriers =========
            #pragma unroll
            for (int i = 0; i < 4; ++i)
                #pragma unroll
                for (int j = 0; j < 2; ++j) acc[i][j] = (f32x4){0.f, 0.f, 0.f, 0.f};
            #pragma unroll
            for (int kt = 0; kt < 5; ++kt) {
                if (kt < 4) vmw<4>(); else vmw<0>();
                f16x8 ah[4], al[4];
                if (kt < 4) {
                    #pragma unroll
                    for (int i = 0; i < 4; ++i) {
                        int row = i * 16 + lr;
                        int byo = row * 256 + ((kt * 64 + lh * 16) ^ ((row & 7) << 4));
                        ah[i] = *(const f16x8*)((const char*)sCtx + byo);
                        al[i] = *(const f16x8*)((const char*)sCtx + 16384 + byo);
                    }
                } else {
                    #pragma unroll
                    for (int i = 0; i < 4; ++i) {
                        int row = i * 16 + lr;
                        ah[i] = *(const f16x8*)&sXi[0][row * XSTR + lh * 8];
                        al[i] = *(const f16x8*)&sXi[1][row * XSTR + lh * 8];
                    }
                }
                const char* bb = wbuf + (kt & 1) * 4096;
                __builtin_amdgcn_s_setprio(1);
                #pragma unroll
                for (int j = 0; j < 2; ++j) {
                    int cb = bRd(j * 16 + lr);
                    f16x8 bh = *(const f16x8*)(bb + cb);
                    f16x8 bl = *(const f16x8*)(bb + 2048 + cb);
                    #pragma unroll
                    for (int i = 0; i < 4; ++i) {
                        acc[i][j] = __builtin_amdgcn_mfma_f32_16x16x32_f16(ah[i], bh, acc[i][j], 0, 0, 0);
                        acc[i][j] = __builtin_amdgcn_mfma_f32_16x16x32_f16(ah[i], bl, acc[i][j], 0, 0, 0);
                        acc[i][j] = __builtin_amdgcn_mfma_f32_16x16x32_f16(al[i], bh, acc[i][j], 0, 0, 0);
                    }
                }
                __builtin_amdgcn_s_setprio(0);
                if (kt + 2 < 5) {
                    lgkmw();   // own reads of this buf retired before overwrite
                    stageB(W1hL, W1lL, kt & 1, kt + 2, K1, wcol0, 32);
                }
            }
            // h1 = relu(acc+b1) -> sH (dedicated region, no barrier needed)
            #pragma unroll
            for (int j = 0; j < 2; ++j) {
                int col = wcol0 + j * 16 + lr;
                float bv = j ? bv1_1 : bv1_0;
                #pragma unroll
                for (int i = 0; i < 4; ++i)
                    #pragma unroll
                    for (int q = 0; q < 4; ++q) {
                        float v = fmaxf(acc[i][j][q] + bv, 0.f);
                        int row = i * 16 + lh * 4 + q;
                        int e = ((row << 8) + col) ^ ((row & 7) << 3);
                        sH[e] = (f16)v;
                    }
            }
            stageB(W2hL, W2lL, 0, 0, HDIM, wcol0, 32);
            stageB(W2hL, W2lL, 1, 1, HDIM, wcol0, 32);
            lgkm_bar();   // publish h1

            // ======= GEMM2: K=256, 8 phases, A single, NO barriers ========
            #pragma unroll
            for (int i = 0; i < 4; ++i)
                #pragma unroll
                for (int j = 0; j < 2; ++j) acc[i][j] = (f32x4){0.f, 0.f, 0.f, 0.f};
            #pragma unroll
            for (int kt = 0; kt < 8; ++kt) {
                if (kt < 7) vmw<4>(); else vmw<0>();
                int k0 = kt * 32 + lh * 8;
                f16x8 ah[4];
                #pragma unroll
                for (int i = 0; i < 4; ++i) {
                    int row = i * 16 + lr;
                    int e = ((row << 8) + k0) ^ ((row & 7) << 3);
                    ah[i] = *(const f16x8*)&sH[e];
                }
                const char* bb = wbuf + (kt & 1) * 4096;
                __builtin_amdgcn_s_setprio(1);
                #pragma unroll
                for (int j = 0; j < 2; ++j) {
                    int cb = bRd(j * 16 + lr);
                    f16x8 bh = *(const f16x8*)(bb + cb);
                    f16x8 bl = *(const f16x8*)(bb + 2048 + cb);
                    #pragma unroll
                    for (int i = 0; i < 4; ++i) {
                        acc[i][j] = __builtin_amdgcn_mfma_f32_16x16x32_f16(ah[i], bh, acc[i][j], 0, 0, 0);
                        acc[i][j] = __builtin_amdgcn_mfma_f32_16x16x32_f16(ah[i], bl, acc[i][j], 0, 0, 0);
                    }
                }
                __builtin_amdgcn_s_setprio(0);
                if (kt + 2 < 8) {
                    lgkmw();
                    stageB(W2hL, W2lL, kt & 1, kt + 2, HDIM, wcol0, 32);
                }
            }
            barr();   // all waves done reading h1
            // h2 = relu(acc+b2) -> sH
            #pragma unroll
            for (int j = 0; j < 2; ++j) {
                int col = wcol0 + j * 16 + lr;
                float bv = j ? bv2_1 : bv2_0;
                #pragma unroll
                for (int i = 0; i < 4; ++i)
                    #pragma unroll
                    for (int q = 0; q < 4; ++q) {
                        float v = fmaxf(acc[i][j][q] + bv, 0.f);
                        int row = i * 16 + lh * 4 + q;
                        int e = ((row << 8) + col) ^ ((row & 7) << 3);
                        sH[e] = (f16)v;
                    }
            }
            {
                const int NC3 = (w < 4) ? 32 : 16;
                stageB(W3hL, W3lL, 0, 0, HDIM, wc3, NC3);
                stageB(W3hL, W3lL, 1, 1, HDIM, wc3, NC3);
            }
            lgkm_bar();   // publish h2

            // === GEMM3: K=256, 8 phases; waves 0-3: 2 tiles, 4-7: 1 ======
            f32x4 acc3[4][2];
            #pragma unroll
            for (int i = 0; i < 4; ++i)
                #pragma unroll
                for (int j = 0; j < 2; ++j) acc3[i][j] = (f32x4){0.f, 0.f, 0.f, 0.f};
            {
                const int NC3 = (w < 4) ? 32 : 16;
                const int nc64 = NC3 * 64;
                #pragma unroll
                for (int kt = 0; kt < 8; ++kt) {
                    if (kt < 7) { if (w < 4) vmw<4>(); else vmw<2>(); }
                    else vmw<0>();
                    int k0 = kt * 32 + lh * 8;
                    f16x8 ah[4];
                    #pragma unroll
                    for (int i = 0; i < 4; ++i) {
                        int row = i * 16 + lr;
                        int e = ((row << 8) + k0) ^ ((row & 7) << 3);
                        ah[i] = *(const f16x8*)&sH[e];
                    }
                    const char* bb = wbuf + (kt & 1) * 4096;
                    __builtin_amdgcn_s_setprio(1);
                    {
                        int cb = bRd(lr);
                        f16x8 bh = *(const f16x8*)(bb + cb);
                        f16x8 bl = *(const f16x8*)(bb + nc64 + cb);
                        #pragma unroll
                        for (int i = 0; i < 4; ++i) {
                            acc3[i][0] = __builtin_amdgcn_mfma_f32_16x16x32_f16(ah[i], bh, acc3[i][0], 0, 0, 0);
                            acc3[i][0] = __builtin_amdgcn_mfma_f32_16x16x32_f16(ah[i], bl, acc3[i][0], 0, 0, 0);
                        }
                    }
                    if (w < 4) {
                        int cb = bRd(16 + lr);
                        f16x8 bh = *(const f16x8*)(bb + cb);
                        f16x8 bl = *(const f16x8*)(bb + nc64 + cb);
                        #pragma unroll
                        for (int i = 0; i < 4; ++i) {
                            acc3[i][1] = __builtin_amdgcn_mfma_f32_16x16x32_f16(ah[i], bh, acc3[i][1], 0, 0, 0);
                            acc3[i][1] = __builtin_amdgcn_mfma_f32_16x16x32_f16(ah[i], bl, acc3[i][1], 0, 0, 0);
                        }
                    }
                    __builtin_amdgcn_s_setprio(0);
                    if (kt + 2 < 8) {
                        lgkmw();
                        stageB(W3hL, W3lL, kt & 1, kt + 2, HDIM, wc3, NC3);
                    }
                }
            }
            barr();   // all waves done reading h2 AND all staging retired
            // p = acc3 + b3 -> sP (overlays wave-buffer area; now dead)
            {
                int col = wc3 + lr;
                #pragma unroll
                for (int i = 0; i < 4; ++i)
                    #pragma unroll
                    for (int q = 0; q < 4; ++q) {
                        int row = i * 16 + lh * 4 + q;
                        sP[row * PSTR + col] = acc3[i][0][q] + bv3_0;
                    }
                if (w < 4) {
                    int col1 = wc3 + 16 + lr;
                    #pragma unroll
                    for (int i = 0; i < 4; ++i)
                        #pragma unroll
                        for (int q = 0; q < 4; ++q) {
                            int row = i * 16 + lh * 4 + q;
                            sP[row * PSTR + col1] = acc3[i][1][q] + bv3_1;
                        }
                }
            }
            lgkm_bar();   // publish p

            // ===== spline: one (row,t) per thread (fast transcendentals) ====
            {
                int r = tid & 63, t = tid >> 6;
                float xin = sX[cur][r][2 * t + (l & 1)];
                const float* pp = &sP[r * PSTR + t * PD];
                bool inside = (xin >= -TBV) && (xin <= TBV);
                float xs = fminf(fmaxf(xin, -TBV), TBV);

                float e0, e1, e2, e3, e4, e5, e6, e7;
                {
                    float a0 = pp[0], a1 = pp[1], a2 = pp[2], a3 = pp[3];
                    float a4 = pp[4], a5 = pp[5], a6 = pp[6], a7 = pp[7];
                    float m = fmaxf(fmaxf(fmaxf(a0, a1), fmaxf(a2, a3)),
                                    fmaxf(fmaxf(a4, a5), fmaxf(a6, a7)));
                    e0 = __expf(a0 - m); e1 = __expf(a1 - m); e2 = __expf(a2 - m); e3 = __expf(a3 - m);
                    e4 = __expf(a4 - m); e5 = __expf(a5 - m); e6 = __expf(a6 - m); e7 = __expf(a7 - m);
                }
                float swv = ((e0 + e1) + (e2 + e3)) + ((e4 + e5) + (e6 + e7));
                float cwc = (1.f - 0.001f * KBINS) / swv;
                float x0 = -TBV, x1 = TBV;
                int idx = 0;
                bool done = false;
                {
                    float cs = 0.f;
                    float ee[7] = {e0, e1, e2, e3, e4, e5, e6};
                    #pragma unroll
                    for (int k = 0; k < 7; ++k) {
                        cs += 0.001f + cwc * ee[k];
                        float nxt = 2.f * TBV * cs - TBV;
                        bool ge = (xs >= nxt);
                        x0 = ge ? nxt : x0;
                        idx += ge ? 1 : 0;
                        x1 = (!ge && !done) ? nxt : x1;
                        done = done || !ge;
                    }
                }
                float y0 = -TBV, y1 = TBV;
                {
                    float a0 = pp[8], a1 = pp[9], a2 = pp[10], a3 = pp[11];
                    float a4 = pp[12], a5 = pp[13], a6 = pp[14], a7 = pp[15];
                    float m = fmaxf(fmaxf(fmaxf(a0, a1), fmaxf(a2, a3)),
                                    fmaxf(fmaxf(a4, a5), fmaxf(a6, a7)));
                    float f0 = __expf(a0 - m), f1 = __expf(a1 - m), f2 = __expf(a2 - m), f3 = __expf(a3 - m);
                    float f4 = __expf(a4 - m), f5 = __expf(a5 - m), f6 = __expf(a6 - m), f7 = __expf(a7 - m);
                    float shv = ((f0 + f1) + (f2 + f3)) + ((f4 + f5) + (f6 + f7));
                    float chc = (1.f - 0.001f * KBINS) / shv;
                    float cs = 0.f;
                    float ff[7] = {f0, f1, f2, f3, f4, f5, f6};
                    #pragma unroll
                    for (int k = 0; k < 7; ++k) {
                        cs += 0.001f + chc * ff[k];
                        float nxt = 2.f * TBV * cs - TBV;
                        y0 = (k < idx) ? nxt : y0;
                        y1 = (k == idx) ? nxt : y1;
                    }
                }
                float udm = pp[16 + (idx > 0 ? idx - 1 : 0)];
                float udp = pp[16 + (idx < 7 ? idx : 6)];
                float d0 = (idx > 0) ? 0.001f + softplusf(udm) : 1.f;
                float d1 = (idx < 7) ? 0.001f + softplusf(udp) : 1.f;

                float bw = x1 - x0, bh2 = y1 - y0;
                float delta = bh2 / bw;
                float th = (xs - x0) / bw;
                float th1m = th * (1.f - th);
                float num = bh2 * (delta * th * th + d0 * th1m);
                float den = delta + (d0 + d1 - 2.f * delta) * th1m;
                float y = y0 + num / den;
                float omth = 1.f - th;
                float dnum = delta * delta * (d1 * th * th + 2.f * delta * th1m + d0 * omth * omth);
                float ldv = __logf(dnum) - 2.f * __logf(den);
                sY[r][t] = inside ? y : xin;
                sLd[r][t] = inside ? ldv : 0.f;
            }
            lgkm_bar();   // publish sY/sLd

            // ===== rebuild x (+perm), next-layer xi, ldet =====
            {
                int r = tid >> 3, f0 = (tid & 7) * 2;
                if (l < NL - 1) {
                    float vv[2];
                    #pragma unroll
                    for (int ff = 0; ff < 2; ++ff) {
                        int f = f0 + ff;
                        int g = sPerm[l * FDIM + f];
                        float v = ((g & 1) == (l & 1)) ? sY[r][g >> 1] : sX[cur][r][g];
                        sX[cur ^ 1][r][f] = v;
                        vv[ff] = v;
                    }
                    // layer l+1: idn parity = 1-((l+1)&1) = (l&1); k = tid&7
                    float vxi = vv[l & 1];
                    f16 hx = (f16)vxi;
                    sXi[0][r * XSTR + (tid & 7)] = hx;
                    sXi[1][r * XSTR + (tid & 7)] = (f16)(vxi - (float)hx);
                    if (f0 == 0) {
                        float s = 0.f;
                        #pragma unroll
                        for (int t = 0; t < 8; ++t) s += sLd[r][t];
                        sLdet[r] += s;
                    }
                } else {
                    float ov[2];
                    #pragma unroll
                    for (int ff = 0; ff < 2; ++ff) {
                        int f = f0 + ff;
                        float v = ((f & 1) == (l & 1)) ? sY[r][f >> 1] : sX[cur][r][f];
                        ov[ff] = fminf(fmaxf(v, -1.f), 1.f);
                    }
                    float2 o = {ov[0], ov[1]};
                    *(float2*)&out[(size_t)(rbase + r) * FDIM + f0] = o;
                    if (f0 == 0) {
                        float s = 0.f;
                        #pragma unroll
                        for (int t = 0; t < 8; ++t) s += sLd[r][t];
                        out[(size_t)BATCH * FDIM + rbase + r] = sLdet[r] + s;
                    }
                }
            }
            cur ^= 1;
        }
    }
}

extern "C" void kernel_launch(void* const* d_in, const int* in_sizes, int n_in,
                              void* d_out, int out_size, void* d_ws, size_t ws_size,
                              hipStream_t stream) {
    (void)in_sizes; (void)n_in; (void)out_size; (void)ws_size;
    const float* inputs  = (const float*)d_in[0];
    const float* context = (const float*)d_in[1];
    const float* W1 = (const float*)d_in[2];
    const float* b1 = (const float*)d_in[3];
    const float* W2 = (const float*)d_in[4];
    const float* b2 = (const float*)d_in[5];
    const float* W3 = (const float*)d_in[6];
    const float* b3 = (const float*)d_in[7];
    const int*   perms = (const int*)d_in[8];
    float* out = (float*)d_out;

    f16* W1h = (f16*)d_ws;
    f16* W1l = W1h + (size_t)NL * HDIM * K1;
    f16* W2h = W1l + (size_t)NL * HDIM * K1;
    f16* W2l = W2h + (size_t)NL * HDIM * HDIM;
    f16* W3h = W2l + (size_t)NL * HDIM * HDIM;
    f16* W3l = W3h + (size_t)NL * N3P * HDIM;
    f16* ctxh = W3l + (size_t)NL * N3P * HDIM;
    f16* ctxl = ctxh + (size_t)BATCH * CDIM;

    int n1 = NL * HDIM * K1;
    conv_w1_kernel<<<(n1 + 255) / 256, 256, 0, stream>>>(W1, W1h, W1l);
    int n2 = NL * HDIM * HDIM;
    conv_w2_kernel<<<(n2 + 255) / 256, 256, 0, stream>>>(W2, W2h, W2l);
    int n3 = NL * N3P * HDIM;
    conv_w3_kernel<<<(n3 + 255) / 256, 256, 0, stream>>>(W3, W3h, W3l);
    int nc = BATCH * CDIM / 4;
    conv_ctx_kernel<<<(nc + 255) / 256, 256, 0, stream>>>(context, ctxh, ctxl);

    flow_kernel<<<256, 512, 0, stream>>>(
        inputs, ctxh, ctxl, W1h, W1l, W2h, W2l, W3h, W3l,
        b1, b2, b3, perms, out);
}

// Round 26
// 504.807 us; speedup vs baseline: 1.0091x; 1.0091x over previous
//
#include <hip/hip_runtime.h>
#include <math.h>

#define BATCH 65536
#define FDIM 16
#define CDIM 128
#define HDIM 256
#define NL 8
#define KBINS 8
#define TDIM 8
#define PD 23
#define TBV 3.0f
#define K1 160      // GEMM1 K: 128 ctx + 8 xi + 24 zero
#define N3 184      // real N of GEMM3
#define N3P 192     // padded N of GEMM3
#define PSTR 197    // p LDS row stride (f32 words)
#define MR 64       // rows per row-block
#define XSTR 40     // sXi row stride (f16)

typedef _Float16 f16;
typedef __attribute__((ext_vector_type(8))) _Float16 f16x8;
typedef __attribute__((ext_vector_type(4))) float f32x4;

// ---------------- weight conversion (transposed to [N][K], split hi/lo) ----
__global__ __launch_bounds__(256)
void conv_w1_kernel(const float* __restrict__ W1,
                    f16* __restrict__ Wh, f16* __restrict__ Wl) {
    int idx = blockIdx.x * 256 + threadIdx.x;
    if (idx >= NL * HDIM * K1) return;
    int l = idx / (HDIM * K1);
    int rem = idx - l * (HDIM * K1);
    int n = rem / K1;
    int k = rem - n * K1;
    int row = (k < 128) ? (8 + k) : ((k < 136) ? (k - 128) : -1);
    float v = (row >= 0) ? W1[((size_t)l * 136 + row) * HDIM + n] : 0.f;
    f16 hv = (f16)v;
    Wh[idx] = hv; Wl[idx] = (f16)(v - (float)hv);
}

__global__ __launch_bounds__(256)
void conv_w2_kernel(const float* __restrict__ W2,
                    f16* __restrict__ Wh, f16* __restrict__ Wl) {
    int idx = blockIdx.x * 256 + threadIdx.x;
    if (idx >= NL * HDIM * HDIM) return;
    int l = idx / (HDIM * HDIM);
    int rem = idx - l * (HDIM * HDIM);
    int n = rem >> 8;
    int k = rem & 255;
    float v = W2[((size_t)l * HDIM + k) * HDIM + n];
    f16 hv = (f16)v;
    Wh[idx] = hv; Wl[idx] = (f16)(v - (float)hv);
}

__global__ __launch_bounds__(256)
void conv_w3_kernel(const float* __restrict__ W3,
                    f16* __restrict__ Wh, f16* __restrict__ Wl) {
    int idx = blockIdx.x * 256 + threadIdx.x;
    if (idx >= NL * N3P * HDIM) return;
    int l = idx / (N3P * HDIM);
    int rem = idx - l * (N3P * HDIM);
    int n = rem >> 8;
    int k = rem & 255;
    float v = (n < N3) ? W3[((size_t)l * HDIM + k) * N3 + n] : 0.f;
    f16 hv = (f16)v;
    Wh[idx] = hv; Wl[idx] = (f16)(v - (float)hv);
}

__global__ __launch_bounds__(256)
void conv_ctx_kernel(const float* __restrict__ ctx,
                     f16* __restrict__ ch, f16* __restrict__ cl) {
    size_t idx = ((size_t)blockIdx.x * 256 + threadIdx.x) * 4;
    if (idx >= (size_t)BATCH * CDIM) return;
    float4 v = *(const float4*)&ctx[idx];
    f16 h;
    h = (f16)v.x; ch[idx + 0] = h; cl[idx + 0] = (f16)(v.x - (float)h);
    h = (f16)v.y; ch[idx + 1] = h; cl[idx + 1] = (f16)(v.y - (float)h);
    h = (f16)v.z; ch[idx + 2] = h; cl[idx + 2] = (f16)(v.z - (float)h);
    h = (f16)v.w; ch[idx + 3] = h; cl[idx + 3] = (f16)(v.w - (float)h);
}

__device__ __forceinline__ float softplusf(float v) {
    return fmaxf(v, 0.f) + log1pf(__expf(-fabsf(v)));
}

__device__ __forceinline__ void gld16(const f16* src, f16* dst) {
    __builtin_amdgcn_global_load_lds(
        (const __attribute__((address_space(1))) unsigned int*)src,
        (__attribute__((address_space(3))) unsigned int*)dst, 16, 0, 0);
}

template<int N> __device__ __forceinline__ void vmw() {
    asm volatile("s_waitcnt vmcnt(%0)" :: "n"(N) : "memory");
}
__device__ __forceinline__ void lgkmw() {
    asm volatile("s_waitcnt lgkmcnt(0)" ::: "memory");
}
__device__ __forceinline__ void barr() {
    __builtin_amdgcn_s_barrier();
    __builtin_amdgcn_sched_barrier(0);
}
__device__ __forceinline__ void lgkm_bar() {
    asm volatile("s_waitcnt lgkmcnt(0)" ::: "memory");
    __builtin_amdgcn_s_barrier();
    __builtin_amdgcn_sched_barrier(0);
}

// ---------------- fused flow kernel ----------------
// Persistent: grid 256 (1 WG/CU), 512 threads (8 waves). Each wave owns a
// col slice; private 2-buf LDS weight tiles (depth-1, counted vmcnt, no
// k-loop barriers). Dedicated LDS: sCtx resident per row-block, sH, p
// overlays the (dead) wave-buffer area. G3 split 4x2 + 4x1 col-tiles.
// B swizzle: slot position (s + (c>>1))&3 holds k-seg s -> 2-way (free)
// bank access. Spline uses native-rate transcendentals (__expf/__logf).
__global__ __launch_bounds__(512, 1)
void flow_kernel(const float* __restrict__ in,
                 const f16* __restrict__ ctxh, const f16* __restrict__ ctxl,
                 const f16* __restrict__ W1h, const f16* __restrict__ W1l,
                 const f16* __restrict__ W2h, const f16* __restrict__ W2l,
                 const f16* __restrict__ W3h, const f16* __restrict__ W3l,
                 const float* __restrict__ b1, const float* __restrict__ b2,
                 const float* __restrict__ b3, const int* __restrict__ perms,
                 float* __restrict__ out) {
    __shared__ __align__(16) f16 sCtx[16384];        // 32K resident ctx (2 planes)
    __shared__ __align__(16) char warena[65536];     // 8 waves x 2 x 4KB B bufs
    __shared__ __align__(16) f16 sH[16384];          // 32K h1/h2
    __shared__ __align__(16) f16 sXi[2][MR * XSTR];  // 10.2K
    __shared__ float sX[2][MR][17];
    __shared__ float sY[MR][9];
    __shared__ float sLd[MR][9];
    __shared__ float sLdet[MR];
    __shared__ float sBias[768];
    __shared__ int   sPerm[(NL - 1) * FDIM];

    float* sP = (float*)warena;                      // 64 x PSTR fp32 overlay

    const int tid = threadIdx.x;
    const int lane = tid & 63;
    const int w = tid >> 6;                      // 0..7
    const int lr = lane & 15, lh = lane >> 4;
    const int bid = blockIdx.x;
    const int wgid = (bid & 7) * 32 + (bid >> 3);   // XCD swizzle, grid 256
    const int wcol0 = w * 32;                    // G1/G2 col slice
    const int wc3 = (w < 4) ? w * 32 : 128 + (w - 4) * 16;   // G3 col base

    char* const wbuf = warena + w * 8192;        // 2 x 4KB private bufs

    // B read byte offset within tile for local col lc, k-half lh
    auto bRd = [&](int lc) -> int {
        return lc * 64 + (((lh + (lc >> 1)) & 3) << 4);
    };

    // stage wave's own NC-col B tile (k-tile kt) into private buf b.
    // slot position pos of col c holds k-segment (pos - (c>>1))&3.
    auto stageB = [&](const f16* Wh, const f16* Wl, int b, int kt, int KD,
                      int colBase, int NC) {
        char* dst = wbuf + b * 4096;
        #pragma unroll
        for (int ii = 0; ii < 2; ++ii) {
            if (ii * 16 < NC) {
                int si = ii * 64 + lane;
                int c = si >> 2, pos = si & 3;
                int seg = (pos - (c >> 1)) & 3;
                const f16* sh = Wh + (size_t)(colBase + c) * KD + kt * 32 + seg * 8;
                const f16* sl = Wl + (size_t)(colBase + c) * KD + kt * 32 + seg * 8;
                gld16(sh, (f16*)(dst + ii * 1024 + lane * 16));
                gld16(sl, (f16*)(dst + NC * 64 + ii * 1024 + lane * 16));
            }
        }
    };

    for (int rb = 0; rb < 4; ++rb) {
        const int rbase = (rb * 256 + wgid) * MR;
        lgkm_bar();   // protect sX/sLdet/sCtx reuse across row-blocks

        // ---- init x, ldet, perms, xi pads (pads written once per rb) ----
        {
            int r = tid >> 3, c2 = (tid & 7) * 2;
            float2 v = *(const float2*)&in[(size_t)(rbase + r) * FDIM + c2];
            sX[0][r][c2 + 0] = fminf(fmaxf(v.x, -1.f), 1.f);
            sX[0][r][c2 + 1] = fminf(fmaxf(v.y, -1.f), 1.f);
        }
        if (tid < MR) {
            sLdet[tid] = 0.f;
            #pragma unroll
            for (int k = 8; k < 32; ++k) {
                sXi[0][tid * XSTR + k] = (f16)0.f;
                sXi[1][tid * XSTR + k] = (f16)0.f;
            }
        }
        if (rb == 0 && tid < (NL - 1) * FDIM) sPerm[tid] = perms[tid];

        // ---- stage ctx ONCE per row-block (resident all layers) ----
        #pragma unroll
        for (int s = 0; s < 4; ++s) {
            int slot = s * 512 + tid;
            int p = slot >> 10, sp = slot & 1023;
            int row = sp >> 4, blk = sp & 15;
            const f16* src = (p ? ctxl : ctxh)
                           + (size_t)(rbase + row) * CDIM + (blk ^ (row & 7)) * 8;
            gld16(src, &sCtx[slot * 8]);
        }

        int cur = 0;
        for (int l = 0; l < NL; ++l) {
            lgkm_bar();   // publish rebuild/init LDS writes

            // ---- biases -> LDS ----
            {
                float bv1 = (tid < 256) ? b1[l * HDIM + tid]
                                        : b2[l * HDIM + (tid - 256)];
                float bv3 = b3[l * N3 + (tid < N3 ? tid : N3 - 1)];
                sBias[tid] = bv1;
                if (tid < N3) sBias[512 + tid] = bv3;
            }
            // ---- xi (split) into sXi (k<8 only; pads pre-zeroed) ----
            if (tid < MR) {
                int r = tid, off = 1 - (l & 1);
                #pragma unroll
                for (int k = 0; k < 8; ++k) {
                    float v = sX[cur][r][2 * k + off];
                    f16 hv = (f16)v;
                    sXi[0][r * XSTR + k] = hv;
                    sXi[1][r * XSTR + k] = (f16)(v - (float)hv);
                }
            }
            const f16* W1hL = W1h + (size_t)l * HDIM * K1;
            const f16* W1lL = W1l + (size_t)l * HDIM * K1;
            const f16* W2hL = W2h + (size_t)l * HDIM * HDIM;
            const f16* W2lL = W2l + (size_t)l * HDIM * HDIM;
            const f16* W3hL = W3h + (size_t)l * N3P * HDIM;
            const f16* W3lL = W3l + (size_t)l * N3P * HDIM;
            stageB(W1hL, W1lL, 0, 0, K1, wcol0, 32);
            stageB(W1hL, W1lL, 1, 1, K1, wcol0, 32);
            lgkm_bar();   // publish xi/bias

            f32x4 acc[4][2];
            // ======= GEMM1: K=160, 5 phases, A split, NO barriers =========
            #pragma unroll
            for (int i = 0; i < 4; ++i)
                #pragma unroll
                for (int j = 0; j < 2; ++j) acc[i][j] = (f32x4){0.f, 0.f, 0.f, 0.f};
            #pragma unroll
            for (int kt = 0; kt < 5; ++kt) {
                if (kt < 4) vmw<4>(); else vmw<0>();
                f16x8 ah[4], al[4];
                if (kt < 4) {
                    #pragma unroll
                    for (int i = 0; i < 4; ++i) {
                        int row = i * 16 + lr;
                        int byo = row * 256 + ((kt * 64 + lh * 16) ^ ((row & 7) << 4));
                        ah[i] = *(const f16x8*)((const char*)sCtx + byo);
                        al[i] = *(const f16x8*)((const char*)sCtx + 16384 + byo);
                    }
                } else {
                    #pragma unroll
                    for (int i = 0; i < 4; ++i) {
                        int row = i * 16 + lr;
                        ah[i] = *(const f16x8*)&sXi[0][row * XSTR + lh * 8];
                        al[i] = *(const f16x8*)&sXi[1][row * XSTR + lh * 8];
                    }
                }
                const char* bb = wbuf + (kt & 1) * 4096;
                __builtin_amdgcn_s_setprio(1);
                #pragma unroll
                for (int j = 0; j < 2; ++j) {
                    int cb = bRd(j * 16 + lr);
                    f16x8 bh = *(const f16x8*)(bb + cb);
                    f16x8 bl = *(const f16x8*)(bb + 2048 + cb);
                    #pragma unroll
                    for (int i = 0; i < 4; ++i) {
                        acc[i][j] = __builtin_amdgcn_mfma_f32_16x16x32_f16(ah[i], bh, acc[i][j], 0, 0, 0);
                        acc[i][j] = __builtin_amdgcn_mfma_f32_16x16x32_f16(ah[i], bl, acc[i][j], 0, 0, 0);
                        acc[i][j] = __builtin_amdgcn_mfma_f32_16x16x32_f16(al[i], bh, acc[i][j], 0, 0, 0);
                    }
                }
                __builtin_amdgcn_s_setprio(0);
                if (kt + 2 < 5) {
                    lgkmw();   // own reads of this buf retired before overwrite
                    stageB(W1hL, W1lL, kt & 1, kt + 2, K1, wcol0, 32);
                }
            }
            // h1 = relu(acc+b1) -> sH (dedicated region, no barrier needed)
            #pragma unroll
            for (int j = 0; j < 2; ++j) {
                int col = wcol0 + j * 16 + lr;
                float bv = sBias[col];
                #pragma unroll
                for (int i = 0; i < 4; ++i)
                    #pragma unroll
                    for (int q = 0; q < 4; ++q) {
                        float v = fmaxf(acc[i][j][q] + bv, 0.f);
                        int row = i * 16 + lh * 4 + q;
                        int e = ((row << 8) + col) ^ ((row & 7) << 3);
                        sH[e] = (f16)v;
                    }
            }
            stageB(W2hL, W2lL, 0, 0, HDIM, wcol0, 32);
            stageB(W2hL, W2lL, 1, 1, HDIM, wcol0, 32);
            lgkm_bar();   // publish h1

            // ======= GEMM2: K=256, 8 phases, A single, NO barriers ========
            #pragma unroll
            for (int i = 0; i < 4; ++i)
                #pragma unroll
                for (int j = 0; j < 2; ++j) acc[i][j] = (f32x4){0.f, 0.f, 0.f, 0.f};
            #pragma unroll
            for (int kt = 0; kt < 8; ++kt) {
                if (kt < 7) vmw<4>(); else vmw<0>();
                int k0 = kt * 32 + lh * 8;
                f16x8 ah[4];
                #pragma unroll
                for (int i = 0; i < 4; ++i) {
                    int row = i * 16 + lr;
                    int e = ((row << 8) + k0) ^ ((row & 7) << 3);
                    ah[i] = *(const f16x8*)&sH[e];
                }
                const char* bb = wbuf + (kt & 1) * 4096;
                __builtin_amdgcn_s_setprio(1);
                #pragma unroll
                for (int j = 0; j < 2; ++j) {
                    int cb = bRd(j * 16 + lr);
                    f16x8 bh = *(const f16x8*)(bb + cb);
                    f16x8 bl = *(const f16x8*)(bb + 2048 + cb);
                    #pragma unroll
                    for (int i = 0; i < 4; ++i) {
                        acc[i][j] = __builtin_amdgcn_mfma_f32_16x16x32_f16(ah[i], bh, acc[i][j], 0, 0, 0);
                        acc[i][j] = __builtin_amdgcn_mfma_f32_16x16x32_f16(ah[i], bl, acc[i][j], 0, 0, 0);
                    }
                }
                __builtin_amdgcn_s_setprio(0);
                if (kt + 2 < 8) {
                    lgkmw();
                    stageB(W2hL, W2lL, kt & 1, kt + 2, HDIM, wcol0, 32);
                }
            }
            barr();   // all waves done reading h1
            // h2 = relu(acc+b2) -> sH
            #pragma unroll
            for (int j = 0; j < 2; ++j) {
                int col = wcol0 + j * 16 + lr;
                float bv = sBias[256 + col];
                #pragma unroll
                for (int i = 0; i < 4; ++i)
                    #pragma unroll
                    for (int q = 0; q < 4; ++q) {
                        float v = fmaxf(acc[i][j][q] + bv, 0.f);
                        int row = i * 16 + lh * 4 + q;
                        int e = ((row << 8) + col) ^ ((row & 7) << 3);
                        sH[e] = (f16)v;
                    }
            }
            {
                const int NC3 = (w < 4) ? 32 : 16;
                stageB(W3hL, W3lL, 0, 0, HDIM, wc3, NC3);
                stageB(W3hL, W3lL, 1, 1, HDIM, wc3, NC3);
            }
            lgkm_bar();   // publish h2

            // === GEMM3: K=256, 8 phases; waves 0-3: 2 tiles, 4-7: 1 ======
            f32x4 acc3[4][2];
            #pragma unroll
            for (int i = 0; i < 4; ++i)
                #pragma unroll
                for (int j = 0; j < 2; ++j) acc3[i][j] = (f32x4){0.f, 0.f, 0.f, 0.f};
            {
                const int NC3 = (w < 4) ? 32 : 16;
                const int nc64 = NC3 * 64;
                #pragma unroll
                for (int kt = 0; kt < 8; ++kt) {
                    if (kt < 7) { if (w < 4) vmw<4>(); else vmw<2>(); }
                    else vmw<0>();
                    int k0 = kt * 32 + lh * 8;
                    f16x8 ah[4];
                    #pragma unroll
                    for (int i = 0; i < 4; ++i) {
                        int row = i * 16 + lr;
                        int e = ((row << 8) + k0) ^ ((row & 7) << 3);
                        ah[i] = *(const f16x8*)&sH[e];
                    }
                    const char* bb = wbuf + (kt & 1) * 4096;
                    __builtin_amdgcn_s_setprio(1);
                    {
                        int cb = bRd(lr);
                        f16x8 bh = *(const f16x8*)(bb + cb);
                        f16x8 bl = *(const f16x8*)(bb + nc64 + cb);
                        #pragma unroll
                        for (int i = 0; i < 4; ++i) {
                            acc3[i][0] = __builtin_amdgcn_mfma_f32_16x16x32_f16(ah[i], bh, acc3[i][0], 0, 0, 0);
                            acc3[i][0] = __builtin_amdgcn_mfma_f32_16x16x32_f16(ah[i], bl, acc3[i][0], 0, 0, 0);
                        }
                    }
                    if (w < 4) {
                        int cb = bRd(16 + lr);
                        f16x8 bh = *(const f16x8*)(bb + cb);
                        f16x8 bl = *(const f16x8*)(bb + nc64 + cb);
                        #pragma unroll
                        for (int i = 0; i < 4; ++i) {
                            acc3[i][1] = __builtin_amdgcn_mfma_f32_16x16x32_f16(ah[i], bh, acc3[i][1], 0, 0, 0);
                            acc3[i][1] = __builtin_amdgcn_mfma_f32_16x16x32_f16(ah[i], bl, acc3[i][1], 0, 0, 0);
                        }
                    }
                    __builtin_amdgcn_s_setprio(0);
                    if (kt + 2 < 8) {
                        lgkmw();
                        stageB(W3hL, W3lL, kt & 1, kt + 2, HDIM, wc3, NC3);
                    }
                }
            }
            barr();   // all waves done reading h2 AND all staging retired
            // p = acc3 + b3 -> sP (overlays wave-buffer area; now dead)
            {
                int col = wc3 + lr;
                float bv = (col < N3) ? sBias[512 + col] : 0.f;
                #pragma unroll
                for (int i = 0; i < 4; ++i)
                    #pragma unroll
                    for (int q = 0; q < 4; ++q) {
                        int row = i * 16 + lh * 4 + q;
                        sP[row * PSTR + col] = acc3[i][0][q] + bv;
                    }
                if (w < 4) {
                    int col1 = wc3 + 16 + lr;
                    float bv1 = sBias[512 + col1];
                    #pragma unroll
                    for (int i = 0; i < 4; ++i)
                        #pragma unroll
                        for (int q = 0; q < 4; ++q) {
                            int row = i * 16 + lh * 4 + q;
                            sP[row * PSTR + col1] = acc3[i][1][q] + bv1;
                        }
                }
            }
            lgkm_bar();   // publish p

            // ===== spline: one (row,t) per thread (fast transcendentals) ====
            {
                int r = tid & 63, t = tid >> 6;
                float xin = sX[cur][r][2 * t + (l & 1)];
                const float* pp = &sP[r * PSTR + t * PD];
                bool inside = (xin >= -TBV) && (xin <= TBV);
                float xs = fminf(fmaxf(xin, -TBV), TBV);

                float e0, e1, e2, e3, e4, e5, e6, e7;
                {
                    float a0 = pp[0], a1 = pp[1], a2 = pp[2], a3 = pp[3];
                    float a4 = pp[4], a5 = pp[5], a6 = pp[6], a7 = pp[7];
                    float m = fmaxf(fmaxf(fmaxf(a0, a1), fmaxf(a2, a3)),
                                    fmaxf(fmaxf(a4, a5), fmaxf(a6, a7)));
                    e0 = __expf(a0 - m); e1 = __expf(a1 - m); e2 = __expf(a2 - m); e3 = __expf(a3 - m);
                    e4 = __expf(a4 - m); e5 = __expf(a5 - m); e6 = __expf(a6 - m); e7 = __expf(a7 - m);
                }
                float swv = ((e0 + e1) + (e2 + e3)) + ((e4 + e5) + (e6 + e7));
                float cwc = (1.f - 0.001f * KBINS) / swv;
                float x0 = -TBV, x1 = TBV;
                int idx = 0;
                bool done = false;
                {
                    float cs = 0.f;
                    float ee[7] = {e0, e1, e2, e3, e4, e5, e6};
                    #pragma unroll
                    for (int k = 0; k < 7; ++k) {
                        cs += 0.001f + cwc * ee[k];
                        float nxt = 2.f * TBV * cs - TBV;
                        bool ge = (xs >= nxt);
                        x0 = ge ? nxt : x0;
                        idx += ge ? 1 : 0;
                        x1 = (!ge && !done) ? nxt : x1;
                        done = done || !ge;
                    }
                }
                float y0 = -TBV, y1 = TBV;
                {
                    float a0 = pp[8], a1 = pp[9], a2 = pp[10], a3 = pp[11];
                    float a4 = pp[12], a5 = pp[13], a6 = pp[14], a7 = pp[15];
                    float m = fmaxf(fmaxf(fmaxf(a0, a1), fmaxf(a2, a3)),
                                    fmaxf(fmaxf(a4, a5), fmaxf(a6, a7)));
                    float f0 = __expf(a0 - m), f1 = __expf(a1 - m), f2 = __expf(a2 - m), f3 = __expf(a3 - m);
                    float f4 = __expf(a4 - m), f5 = __expf(a5 - m), f6 = __expf(a6 - m), f7 = __expf(a7 - m);
                    float shv = ((f0 + f1) + (f2 + f3)) + ((f4 + f5) + (f6 + f7));
                    float chc = (1.f - 0.001f * KBINS) / shv;
                    float cs = 0.f;
                    float ff[7] = {f0, f1, f2, f3, f4, f5, f6};
                    #pragma unroll
                    for (int k = 0; k < 7; ++k) {
                        cs += 0.001f + chc * ff[k];
                        float nxt = 2.f * TBV * cs - TBV;
                        y0 = (k < idx) ? nxt : y0;
                        y1 = (k == idx) ? nxt : y1;
                    }
                }
                float udm = pp[16 + (idx > 0 ? idx - 1 : 0)];
                float udp = pp[16 + (idx < 7 ? idx : 6)];
                float d0 = (idx > 0) ? 0.001f + softplusf(udm) : 1.f;
                float d1 = (idx < 7) ? 0.001f + softplusf(udp) : 1.f;

                float bw = x1 - x0, bh2 = y1 - y0;
                float delta = bh2 / bw;
                float th = (xs - x0) / bw;
                float th1m = th * (1.f - th);
                float num = bh2 * (delta * th * th + d0 * th1m);
                float den = delta + (d0 + d1 - 2.f * delta) * th1m;
                float y = y0 + num / den;
                float omth = 1.f - th;
                float dnum = delta * delta * (d1 * th * th + 2.f * delta * th1m + d0 * omth * omth);
                float ldv = __logf(dnum) - 2.f * __logf(den);
                sY[r][t] = inside ? y : xin;
                sLd[r][t] = inside ? ldv : 0.f;
            }
            lgkm_bar();   // publish sY/sLd

            // ===== rebuild x (+perm) and ldet =====
            {
                int r = tid >> 3, f0 = (tid & 7) * 2;
                if (l < NL - 1) {
                    #pragma unroll
                    for (int ff = 0; ff < 2; ++ff) {
                        int f = f0 + ff;
                        int g = sPerm[l * FDIM + f];
                        float v = ((g & 1) == (l & 1)) ? sY[r][g >> 1] : sX[cur][r][g];
                        sX[cur ^ 1][r][f] = v;
                    }
                    if (f0 == 0) {
                        float s = 0.f;
                        #pragma unroll
                        for (int t = 0; t < 8; ++t) s += sLd[r][t];
                        sLdet[r] += s;
                    }
                } else {
                    float ov[2];
                    #pragma unroll
                    for (int ff = 0; ff < 2; ++ff) {
                        int f = f0 + ff;
                        float v = ((f & 1) == (l & 1)) ? sY[r][f >> 1] : sX[cur][r][f];
                        ov[ff] = fminf(fmaxf(v, -1.f), 1.f);
                    }
                    float2 o = {ov[0], ov[1]};
                    *(float2*)&out[(size_t)(rbase + r) * FDIM + f0] = o;
                    if (f0 == 0) {
                        float s = 0.f;
                        #pragma unroll
                        for (int t = 0; t < 8; ++t) s += sLd[r][t];
                        out[(size_t)BATCH * FDIM + rbase + r] = sLdet[r] + s;
                    }
                }
            }
            cur ^= 1;
        }
    }
}

extern "C" void kernel_launch(void* const* d_in, const int* in_sizes, int n_in,
                              void* d_out, int out_size, void* d_ws, size_t ws_size,
                              hipStream_t stream) {
    (void)in_sizes; (void)n_in; (void)out_size; (void)ws_size;
    const float* inputs  = (const float*)d_in[0];
    const float* context = (const float*)d_in[1];
    const float* W1 = (const float*)d_in[2];
    const float* b1 = (const float*)d_in[3];
    const float* W2 = (const float*)d_in[4];
    const float* b2 = (const float*)d_in[5];
    const float* W3 = (const float*)d_in[6];
    const float* b3 = (const float*)d_in[7];
    const int*   perms = (const int*)d_in[8];
    float* out = (float*)d_out;

    f16* W1h = (f16*)d_ws;
    f16* W1l = W1h + (size_t)NL * HDIM * K1;
    f16* W2h = W1l + (size_t)NL * HDIM * K1;
    f16* W2l = W2h + (size_t)NL * HDIM * HDIM;
    f16* W3h = W2l + (size_t)NL * HDIM * HDIM;
    f16* W3l = W3h + (size_t)NL * N3P * HDIM;
    f16* ctxh = W3l + (size_t)NL * N3P * HDIM;
    f16* ctxl = ctxh + (size_t)BATCH * CDIM;

    int n1 = NL * HDIM * K1;
    conv_w1_kernel<<<(n1 + 255) / 256, 256, 0, stream>>>(W1, W1h, W1l);
    int n2 = NL * HDIM * HDIM;
    conv_w2_kernel<<<(n2 + 255) / 256, 256, 0, stream>>>(W2, W2h, W2l);
    int n3 = NL * N3P * HDIM;
    conv_w3_kernel<<<(n3 + 255) / 256, 256, 0, stream>>>(W3, W3h, W3l);
    int nc = BATCH * CDIM / 4;
    conv_ctx_kernel<<<(nc + 255) / 256, 256, 0, stream>>>(context, ctxh, ctxl);

    flow_kernel<<<256, 512, 0, stream>>>(
        inputs, ctxh, ctxl, W1h, W1l, W2h, W2l, W3h, W3l,
        b1, b2, b3, perms, out);
}